// Round 9
// baseline (642.608 us; speedup 1.0000x reference)
//
#include <hip/hip_runtime.h>
#include <stdint.h>

constexpr int      BATCH    = 524288;
constexpr int      IN_DIM   = 128;
constexpr int      ARRAY_SZ = 262144;
constexpr uint64_t PRIME    = 2038074743ull;
constexpr uint32_t RANGE    = ARRAY_SZ - 8 + 1;  // 262137
constexpr int      ETILE    = 256;               // elements per block-tile
constexpr int      NTILE    = BATCH / ETILE;     // 2048

// component select with compile-time index (folds in unrolled loops)
__device__ __forceinline__ float fc(const float4& v, int ii) {
    return (ii == 0) ? v.x : (ii == 1) ? v.y : (ii == 2) ? v.z : v.w;
}

__global__ __launch_bounds__(512, 2)
void lma_gemm4(const float* __restrict__ x,
               const float* __restrict__ hw,
               const float* __restrict__ lsh,
               const void* __restrict__ rnd_raw,
               float* __restrict__ out_idx,   // B*128 floats (idx as f32)
               float* __restrict__ out_val)   // B*64 floats
{
    // full lsh matrix in LDS, 64 KB, column-blocks placement-permuted so the
    // 4 broadcast groups of a wave read disjoint bank quarters.
    __shared__ float s_l[128][128];

    const int tid  = threadIdx.x;
    const int lane = tid & 63;
    const int w    = __builtin_amdgcn_readfirstlane(tid >> 6);  // 0..7

    // --- hash constants: detect int64 vs int32 layout of random_numbers ---
    uint64_t HA, HB, HC0;
    {
        const uint64_t first8 = *reinterpret_cast<const uint64_t*>(rnd_raw);
        if (first8 == PRIME) {
            const long long* r64 = reinterpret_cast<const long long*>(rnd_raw);
            HA  = (uint64_t)r64[1];
            HB  = (uint64_t)r64[2];
            HC0 = (uint64_t)r64[3];
        } else {
            const int* r32 = reinterpret_cast<const int*>(rnd_raw);
            HA  = (uint64_t)(uint32_t)r32[1];
            HB  = (uint64_t)(uint32_t)r32[2];
            HC0 = (uint64_t)(uint32_t)r32[3];
        }
    }

    // --- stage lsh once per block; store block b at slot perm(b) ---
    for (int it = 0; it < 8; ++it) {
        const int lin = it * 512 + tid;      // 4096 float4s total
        const int row = lin >> 5;
        const int hb  = lin & 31;            // half-block (4 floats)
        const int b   = hb >> 1;
        const int pb  = ((b & 3) << 2) | (b >> 2);
        const float4 v = *reinterpret_cast<const float4*>(lsh + row * 128 + hb * 4);
        *reinterpret_cast<float4*>(&s_l[row][pb * 8 + (hb & 1) * 4]) = v;
    }
    __syncthreads();

    // wave w handles h = (lane>>4)*4 + (w&3); element-slice = w>>2.
    // rep partners (h, h+8) are lanes L and L^32 of the SAME wave.
    const int      h      = (lane >> 4) * 4 + (w & 3);
    const int      slice  = w >> 2;
    const int      ph     = ((h & 3) << 2) | (h >> 2);   // permuted slot
    const int      phbase = ph * 8;
    const int      rep    = h >> 3;
    const int      c      = h & 7;
    const int      eg     = ((lane & 15) + 16 * slice) * 8;  // 8 elems/thread
    const uint64_t hc     = HB * (uint64_t)c + HC0;
    const uint32_t repoff = rep ? (uint32_t)ARRAY_SZ : 0u;

    for (int t = blockIdx.x; t < NTILE; t += gridDim.x) {
        const float* xb = x + (size_t)(t * ETILE + eg) * IN_DIM;

        float acc[8][8];
#pragma unroll
        for (int e = 0; e < 8; ++e)
#pragma unroll
            for (int n = 0; n < 8; ++n) acc[e][n] = 0.0f;

#pragma unroll 1
        for (int i4 = 0; i4 < 32; ++i4) {
            // load this K-window for all 8 elements (8 x float4, static idx)
            float4 xv[8];
#pragma unroll
            for (int e = 0; e < 8; ++e)
                xv[e] = *reinterpret_cast<const float4*>(xb + e * IN_DIM + i4 * 4);

#pragma unroll
            for (int ii = 0; ii < 4; ++ii) {
                const float* lr = &s_l[i4 * 4 + ii][phbase];
                const float4 l0 = *reinterpret_cast<const float4*>(lr);
                const float4 l1 = *reinterpret_cast<const float4*>(lr + 4);
                // 2 LDS b128 reads feed 64 FMAs (32 FMA/read; was 16/read).
                // strictly sequential i-order per accumulator (bit-exact,
                // absmax==0.0 rounds 1-8); 64 independent chains = ILP.
#pragma unroll
                for (int e = 0; e < 8; ++e) {
                    const float xs = fc(xv[e], ii);
                    acc[e][0] = __builtin_fmaf(xs, l0.x, acc[e][0]);
                    acc[e][1] = __builtin_fmaf(xs, l0.y, acc[e][1]);
                    acc[e][2] = __builtin_fmaf(xs, l0.z, acc[e][2]);
                    acc[e][3] = __builtin_fmaf(xs, l0.w, acc[e][3]);
                    acc[e][4] = __builtin_fmaf(xs, l1.x, acc[e][4]);
                    acc[e][5] = __builtin_fmaf(xs, l1.y, acc[e][5]);
                    acc[e][6] = __builtin_fmaf(xs, l1.z, acc[e][6]);
                    acc[e][7] = __builtin_fmaf(xs, l1.w, acc[e][7]);
                }
            }
        }

        // ---- phase 2: per-element (small live set): srp, hash, gather ----
        const int ebase = t * ETILE + eg;
#pragma unroll
        for (int e = 0; e < 8; ++e) {
            uint32_t srp = 0;
#pragma unroll
            for (int j = 0; j < 8; ++j)
                srp |= (acc[e][j] > 0.0f) ? (1u << j) : 0u;
            const uint64_t hh  = (HA * (uint64_t)srp + hc) % PRIME;
            const uint32_t loc = (uint32_t)hh % RANGE + repoff;

            const float f0 = (float)loc;
            float* oi = out_idx + (size_t)(ebase + e) * 128 + rep * 64 + c * 8;
            *reinterpret_cast<float4*>(oi)     = make_float4(f0, f0 + 1.f, f0 + 2.f, f0 + 3.f);
            *reinterpret_cast<float4*>(oi + 4) = make_float4(f0 + 4.f, f0 + 5.f, f0 + 6.f, f0 + 7.f);

            float wv[8];
#pragma unroll
            for (int j = 0; j < 8; ++j)
                wv[j] = hw[loc + j];

            float v[8];
#pragma unroll
            for (int j = 0; j < 8; ++j)
                v[j] = (wv[j] + __shfl_xor(wv[j], 32)) * 0.5f;

            if ((e < 4) == (lane < 32)) {   // split store duty across rep halves
                float* ov = out_val + (size_t)(ebase + e) * 64 + c * 8;
                *reinterpret_cast<float4*>(ov)     = make_float4(v[0], v[1], v[2], v[3]);
                *reinterpret_cast<float4*>(ov + 4) = make_float4(v[4], v[5], v[6], v[7]);
            }
        }
    }
}

extern "C" void kernel_launch(void* const* d_in, const int* in_sizes, int n_in,
                              void* d_out, int out_size, void* d_ws, size_t ws_size,
                              hipStream_t stream) {
    const float* x   = (const float*)d_in[0];
    const float* hw  = (const float*)d_in[1];
    const float* lsh = (const float*)d_in[2];
    const void*  rnd = (const void*)d_in[3];

    float* out_idx = (float*)d_out;
    float* out_val = out_idx + (size_t)BATCH * 128;

    lma_gemm4<<<1024, 512, 0, stream>>>(x, hw, lsh, rnd, out_idx, out_val);
}

// Round 10
// 285.340 us; speedup vs baseline: 2.2521x; 2.2521x over previous
//
#include <hip/hip_runtime.h>
#include <stdint.h>

typedef __attribute__((ext_vector_type(8))) short short8;
typedef __attribute__((ext_vector_type(4))) float f32x4;

constexpr int      BATCH    = 524288;
constexpr int      ARRAY_SZ = 262144;
constexpr uint64_t PRIME    = 2038074743ull;
constexpr uint32_t RANGE    = 262137u;          // ARRAY_SZ - 8 + 1
constexpr int      NMT      = BATCH / 16;       // 32768 M-tiles of 16 elements
// Rigorous sign-certainty bound: |proj_mfma - proj_ref| <= A*(400*2^-23 + 128*2^-24
// + 2^-24) < A*5.6e-5 even if MFMA rounds RTZ. Margin -> 8e-5. Flagged entries are
// recomputed with the sequential fmaf chain proven bit-exact in rounds 1-9.
constexpr float    EPS      = 8e-5f;

__global__ __launch_bounds__(256, 2)
void lma_mfma(const float* __restrict__ x,
              const float* __restrict__ hw,
              const float* __restrict__ lsh,
              const void* __restrict__ rnd_raw,
              float* __restrict__ out_idx,   // B*128 floats (idx as f32)
              float* __restrict__ out_val)   // B*64 floats
{
    // T[n][i]: lsh transposed to bf16 (exact: values in {-1,0,1}), 16B-unit
    // XOR swizzle (unit ^ (n&15)) -> conflict-free B-frag ds_read_b128.
    __shared__ unsigned short T[128 * 128];          // 32 KB
    // pw[wave][e][k]: proj transpose, 16B-unit swizzle (unit ^ ((e&7)<<2)).
    __shared__ float pw[4][16 * 128];                // 32 KB

    const int tid  = threadIdx.x;
    const int lane = tid & 63;
    const int wid  = __builtin_amdgcn_readfirstlane(tid >> 6);

    // --- hash constants: detect int64 vs int32 layout of random_numbers ---
    uint64_t HA, HB, HC0;
    {
        const uint64_t first8 = *reinterpret_cast<const uint64_t*>(rnd_raw);
        if (first8 == PRIME) {
            const long long* r64 = reinterpret_cast<const long long*>(rnd_raw);
            HA = (uint64_t)r64[1]; HB = (uint64_t)r64[2]; HC0 = (uint64_t)r64[3];
        } else {
            const int* r32 = reinterpret_cast<const int*>(rnd_raw);
            HA  = (uint64_t)(uint32_t)r32[1];
            HB  = (uint64_t)(uint32_t)r32[2];
            HC0 = (uint64_t)(uint32_t)r32[3];
        }
    }

    // --- stage T = bf16(lsh)^T, swizzled (one-time; bf16 of +-1/0 = bits>>16) ---
    for (int it = 0; it < 16; ++it) {
        const int flat4 = it * 256 + tid;            // 0..4095
        const int i  = flat4 >> 5;                   // input dim
        const int n4 = (flat4 & 31) << 2;            // output col base
        const f32x4 v = *reinterpret_cast<const f32x4*>(lsh + i * 128 + n4);
#pragma unroll
        for (int d = 0; d < 4; ++d) {
            const int n = n4 + d;
            T[n * 128 + (((i >> 3) ^ (n & 15)) << 3) + (i & 7)] =
                (unsigned short)(__float_as_uint(v[d]) >> 16);
        }
    }
    __syncthreads();

    const int r = lane & 15;          // A-operand M row / B-operand N col
    const int g = lane >> 4;          // k-group
    const int e  = lane >> 2;         // phase-2 element (0..15)
    const int c4 = lane & 3;          // phase-2 chunk slot

    for (int mt = blockIdx.x * 4 + wid; mt < NMT; mt += 8192) {
        const int Mb = mt * 16;
        const float* xb = x + (size_t)Mb * 128;

        f32x4 acc[8];
#pragma unroll
        for (int n8 = 0; n8 < 8; ++n8) acc[n8] = (f32x4)(0.0f);
        float asum = 0.0f;

#pragma unroll
        for (int ks = 0; ks < 4; ++ks) {
            const float* xp = xb + r * 128 + ks * 32 + g * 8;
            const f32x4 xa = *reinterpret_cast<const f32x4*>(xp);
            const f32x4 xc = *reinterpret_cast<const f32x4*>(xp + 4);
            float xs[8] = {xa[0], xa[1], xa[2], xa[3], xc[0], xc[1], xc[2], xc[3]};
#pragma unroll
            for (int j = 0; j < 8; ++j) asum += fabsf(xs[j]);

            // exact 3-way truncation split, packed to bf16x2 dwords (low=even k)
            union { uint32_t u[4]; short8 v; } Ahi, Ami, Alo;
#pragma unroll
            for (int p = 0; p < 4; ++p) {
                const uint32_t b0 = __float_as_uint(xs[2 * p]);
                const uint32_t b1 = __float_as_uint(xs[2 * p + 1]);
                const uint32_t h0 = b0 & 0xFFFF0000u, h1 = b1 & 0xFFFF0000u;
                const float    t0 = xs[2 * p] - __uint_as_float(h0);
                const float    t1 = xs[2 * p + 1] - __uint_as_float(h1);
                const uint32_t m0 = __float_as_uint(t0) & 0xFFFF0000u;
                const uint32_t m1 = __float_as_uint(t1) & 0xFFFF0000u;
                const float    u0 = t0 - __uint_as_float(m0);
                const float    u1 = t1 - __uint_as_float(m1);
                const uint32_t l0 = __float_as_uint(u0) & 0xFFFF0000u;
                const uint32_t l1 = __float_as_uint(u1) & 0xFFFF0000u;
                Ahi.u[p] = h1 | (h0 >> 16);
                Ami.u[p] = m1 | (m0 >> 16);
                Alo.u[p] = l1 | (l0 >> 16);
            }
#pragma unroll
            for (int n8 = 0; n8 < 8; ++n8) {
                const short8 bf = *reinterpret_cast<const short8*>(
                    &T[(n8 * 16 + r) * 128 + (((ks * 4 + g) ^ r) << 3)]);
                acc[n8] = __builtin_amdgcn_mfma_f32_16x16x32_bf16(Ahi.v, bf, acc[n8], 0, 0, 0);
                acc[n8] = __builtin_amdgcn_mfma_f32_16x16x32_bf16(Ami.v, bf, acc[n8], 0, 0, 0);
                acc[n8] = __builtin_amdgcn_mfma_f32_16x16x32_bf16(Alo.v, bf, acc[n8], 0, 0, 0);
            }
        }

        // A (= sum |x|) per element row r; redistribute to phase-2 element e
        asum += __shfl_xor(asum, 16);
        asum += __shfl_xor(asum, 32);
        const float aElem = __shfl(asum, e);

        // proj -> LDS transpose (swizzled); D layout: col=lane&15, row=g*4+reg
#pragma unroll
        for (int n8 = 0; n8 < 8; ++n8)
#pragma unroll
            for (int reg = 0; reg < 4; ++reg) {
                const int er  = g * 4 + reg;
                const int col = n8 * 16 + r;
                const int u   = (col >> 2) ^ ((er & 7) << 2);
                pw[wid][er * 128 + u * 4 + (col & 3)] = acc[n8][reg];
            }
        __syncthreads();

        // ---- phase 2: lane-local srp/flags/hash/gather/store ----
        const size_t eg  = (size_t)(Mb + e);
        const float  bnd = aElem * EPS;
        float wA[8], wB[8];
#pragma unroll
        for (int m = 0; m < 4; ++m) {
            const int cc  = c4 + 4 * m;
            const int rep = cc >> 3;
            const int c   = cc & 7;
            const f32x4 pa = *reinterpret_cast<const f32x4*>(
                &pw[wid][e * 128 + (((cc * 2) ^ ((e & 7) << 2)) << 2)]);
            const f32x4 pb = *reinterpret_cast<const f32x4*>(
                &pw[wid][e * 128 + (((cc * 2 + 1) ^ ((e & 7) << 2)) << 2)]);
            const float p[8] = {pa[0], pa[1], pa[2], pa[3], pb[0], pb[1], pb[2], pb[3]};
            uint32_t srp = 0, flg = 0;
#pragma unroll
            for (int j = 0; j < 8; ++j) {
                srp |= (p[j] > 0.0f) ? (1u << j) : 0u;
                flg |= (fabsf(p[j]) <= bnd) ? (1u << j) : 0u;
            }
            if (flg) {  // rare exact fallback: sequential fmaf, i = 0..127
                const float* xr = x + eg * 128;
                for (uint32_t fb = flg; fb; fb &= fb - 1) {
                    const int k = cc * 8 + __builtin_ctz(fb);
                    float s = 0.0f;
#pragma unroll
                    for (int i4 = 0; i4 < 16; ++i4) {
                        const uint4 tb = *reinterpret_cast<const uint4*>(
                            &T[k * 128 + ((i4 ^ (k & 15)) << 3)]);
                        const f32x4 x0 = *reinterpret_cast<const f32x4*>(xr + i4 * 8);
                        const f32x4 x1 = *reinterpret_cast<const f32x4*>(xr + i4 * 8 + 4);
                        const uint32_t tu[4] = {tb.x, tb.y, tb.z, tb.w};
#pragma unroll
                        for (int q = 0; q < 4; ++q) {
                            s = __builtin_fmaf(x0[0] * 0.0f + ((q < 2) ? x0[2 * q] : x1[2 * (q - 2)]),
                                               __uint_as_float(tu[q] << 16), s);
                            s = __builtin_fmaf(((q < 2) ? x0[2 * q + 1] : x1[2 * (q - 2) + 1]),
                                               __uint_as_float(tu[q] & 0xFFFF0000u), s);
                        }
                    }
                    const int j = k - cc * 8;
                    srp = (srp & ~(1u << j)) | ((s > 0.0f) ? (1u << j) : 0u);
                }
            }
            const uint64_t hh  = (HA * (uint64_t)srp + HB * (uint64_t)c + HC0) % PRIME;
            const uint32_t loc = (uint32_t)hh % RANGE + (rep ? (uint32_t)ARRAY_SZ : 0u);

            const float f0 = (float)loc;
            float* oi = out_idx + eg * 128 + cc * 8;
            *reinterpret_cast<f32x4*>(oi)     = (f32x4){f0, f0 + 1.f, f0 + 2.f, f0 + 3.f};
            *reinterpret_cast<f32x4*>(oi + 4) = (f32x4){f0 + 4.f, f0 + 5.f, f0 + 6.f, f0 + 7.f};

            float wv[8];
#pragma unroll
            for (int j = 0; j < 8; ++j) wv[j] = hw[loc + j];
            if (m == 0) { for (int j = 0; j < 8; ++j) wA[j] = wv[j]; }
            if (m == 1) { for (int j = 0; j < 8; ++j) wB[j] = wv[j]; }
            if (m == 2) {
                float* ov = out_val + eg * 64 + c4 * 8;
                *reinterpret_cast<f32x4*>(ov) =
                    (f32x4){(wA[0]+wv[0])*0.5f,(wA[1]+wv[1])*0.5f,(wA[2]+wv[2])*0.5f,(wA[3]+wv[3])*0.5f};
                *reinterpret_cast<f32x4*>(ov + 4) =
                    (f32x4){(wA[4]+wv[4])*0.5f,(wA[5]+wv[5])*0.5f,(wA[6]+wv[6])*0.5f,(wA[7]+wv[7])*0.5f};
            }
            if (m == 3) {
                float* ov = out_val + eg * 64 + (c4 + 4) * 8;
                *reinterpret_cast<f32x4*>(ov) =
                    (f32x4){(wB[0]+wv[0])*0.5f,(wB[1]+wv[1])*0.5f,(wB[2]+wv[2])*0.5f,(wB[3]+wv[3])*0.5f};
                *reinterpret_cast<f32x4*>(ov + 4) =
                    (f32x4){(wB[4]+wv[4])*0.5f,(wB[5]+wv[5])*0.5f,(wB[6]+wv[6])*0.5f,(wB[7]+wv[7])*0.5f};
            }
        }
        __syncthreads();   // pw reusable next iteration
    }
}

extern "C" void kernel_launch(void* const* d_in, const int* in_sizes, int n_in,
                              void* d_out, int out_size, void* d_ws, size_t ws_size,
                              hipStream_t stream) {
    const float* x   = (const float*)d_in[0];
    const float* hw  = (const float*)d_in[1];
    const float* lsh = (const float*)d_in[2];
    const void*  rnd = (const void*)d_in[3];

    float* out_idx = (float*)d_out;
    float* out_val = out_idx + (size_t)BATCH * 128;

    lma_mfma<<<2048, 256, 0, stream>>>(x, hw, lsh, rnd, out_idx, out_val);
}